// Round 5
// baseline (765.079 us; speedup 1.0000x reference)
//
#include <hip/hip_runtime.h>

// ---------------------------------------------------------------------------
// GraphEncoder round 5:
//  - wgemm2: register-A, global-B (L2-resident weights), zero-barrier GEMM.
//    One block = 128 rows x ALL output cols (tile loop) -> A read ONCE.
//  - aggregate_sliced: column slices of 32, slice = bid & (S-1) so each XCD's
//    L2 caches one 3.2MB slice of h; 4 edge-groups/wave, 64B/edge gathers,
//    xor-shuffle reduce; non-temporal metadata loads.
// ---------------------------------------------------------------------------

typedef __attribute__((ext_vector_type(8))) short short8;
typedef __attribute__((ext_vector_type(4))) float f32x4;

__device__ __forceinline__ float bf2f(unsigned short s) {
    union { unsigned u; float f; } v;
    v.u = ((unsigned)s) << 16;
    return v.f;
}
__device__ __forceinline__ unsigned short f2bf(float f) {
    union { float f; unsigned u; } v;
    v.f = f;
    unsigned r = (v.u + 0x7FFFu + ((v.u >> 16) & 1u)) >> 16;
    return (unsigned short)r;
}

// ---------------------------- CSR build ------------------------------------

__global__ void count_kernel(const int* __restrict__ dst, int E, int* __restrict__ cnt) {
    int e = blockIdx.x * blockDim.x + threadIdx.x;
    if (e < E) atomicAdd(&cnt[dst[e]], 1);
}

__global__ void dinv_kernel(const int* __restrict__ cnt, float* __restrict__ dinv, int n) {
    int i = blockIdx.x * blockDim.x + threadIdx.x;
    if (i < n) dinv[i] = rsqrtf((float)cnt[i] + 1.0f);  // deg = in-degree + self loop
}

// Exclusive scan, 4 elems/thread, single 1024-thread block (4096/pass).
__global__ void scan_kernel(const int* __restrict__ cnt, int n, int* __restrict__ row_ptr) {
    __shared__ int wsum[16];
    __shared__ int s_base;
    int tid = threadIdx.x;
    int lane = tid & 63;
    int w = tid >> 6;
    if (tid == 0) s_base = 0;
    __syncthreads();
    for (int start = 0; start < n; start += 4096) {
        int i = start + tid * 4;
        int v0 = (i + 0 < n) ? cnt[i + 0] : 0;
        int v1 = (i + 1 < n) ? cnt[i + 1] : 0;
        int v2 = (i + 2 < n) ? cnt[i + 2] : 0;
        int v3 = (i + 3 < n) ? cnt[i + 3] : 0;
        int s = v0 + v1 + v2 + v3;
        int incl = s;
        #pragma unroll
        for (int off = 1; off < 64; off <<= 1) {
            int t = __shfl_up(incl, off);
            if (lane >= off) incl += t;
        }
        if (lane == 63) wsum[w] = incl;
        __syncthreads();
        int woff = 0;
        for (int j = 0; j < w; j++) woff += wsum[j];
        int excl = s_base + woff + incl - s;
        if (i + 0 < n) row_ptr[i + 0] = excl;
        if (i + 1 < n) row_ptr[i + 1] = excl + v0;
        if (i + 2 < n) row_ptr[i + 2] = excl + v0 + v1;
        if (i + 3 < n) row_ptr[i + 3] = excl + v0 + v1 + v2;
        __syncthreads();
        if (tid == 1023) s_base = excl + s;
        __syncthreads();
    }
    if (threadIdx.x == 0) row_ptr[n] = s_base;
}

__global__ void scatter_kernel(const int* __restrict__ src, const int* __restrict__ dst, int E,
                               const int* __restrict__ row_ptr, int* __restrict__ fill,
                               const float* __restrict__ dinv, int* __restrict__ csr_src,
                               float* __restrict__ csr_coef) {
    int e = blockIdx.x * blockDim.x + threadIdx.x;
    if (e < E) {
        int d = dst[e], s = src[e];
        int pos = atomicAdd(&fill[d], 1);
        int idx = row_ptr[d] + pos;
        csr_src[idx] = s;
        csr_coef[idx] = dinv[s] * dinv[d];
    }
}

// ---------------------------- conversions ----------------------------------

__global__ void convert_bf16_vec(const float* __restrict__ in, unsigned short* __restrict__ out, int n4) {
    int i = blockIdx.x * blockDim.x + threadIdx.x;
    if (i < n4) {
        float4 v = ((const float4*)in)[i];
        ushort4 o;
        o.x = f2bf(v.x); o.y = f2bf(v.y); o.z = f2bf(v.z); o.w = f2bf(v.w);
        ((ushort4*)out)[i] = o;
    }
}

// All 5 weight matrices: W [K,N] fp32 -> Wt [N,K] bf16, one launch.
__global__ void convert_weights(const float* __restrict__ W1, const float* __restrict__ W2,
                                const float* __restrict__ W3, const float* __restrict__ P1,
                                const float* __restrict__ P2,
                                unsigned short* __restrict__ Wt1, unsigned short* __restrict__ Wt2,
                                unsigned short* __restrict__ Wt3, unsigned short* __restrict__ Pt1,
                                unsigned short* __restrict__ Pt2,
                                int F_IN, int H, int D) {
    int idx = blockIdx.x * blockDim.x + threadIdx.x;
    int n1 = F_IN * H, n2 = H * H, n5 = H * D;
    const float* W; unsigned short* O; int N;
    int t = idx;
    if (t < n1)            { W = W1; O = Wt1; N = H; }
    else if ((t -= n1) < n2) { W = W2; O = Wt2; N = H; }
    else if ((t -= n2) < n2) { W = W3; O = Wt3; N = H; }
    else if ((t -= n2) < n2) { W = P1; O = Pt1; N = H; }
    else if ((t -= n2) < n5) { W = P2; O = Pt2; N = D; }
    else return;
    int k = t / N, n = t - k * N;
    int K = (W == W1) ? F_IN : H;
    O[(size_t)n * K + k] = f2bf(W[t]);
}

// ---------------------------- sliced aggregation ---------------------------
// out[node, slice] = sum_e coef*h[src_e, slice] + dinv^2*h[node, slice]
// HC = row width (128/256); LS = log2(#slices); slice width = 32 cols (64 B).
// slice = bid & (S-1): round-robin block->XCD dispatch pins each slice's
// 3.2 MB working set to one XCD's L2. 4 edge-groups of 16 lanes per wave;
// each group gathers a different edge's 64 B row-slice (one cache line).
// Lanes with k >= end have (mi=0, mc=0) -> harmless row-0 gathers, no tails.

template<int HC, int LS>
__launch_bounds__(256)
__global__ void aggregate_sliced(const unsigned short* __restrict__ h,
                                 const int* __restrict__ row_ptr,
                                 const int* __restrict__ csr_src,
                                 const float* __restrict__ csr_coef,
                                 const float* __restrict__ dinv,
                                 unsigned short* __restrict__ out, int n) {
    constexpr int S = 1 << LS;
    int bid = blockIdx.x;
    int slice = bid & (S - 1);
    int node = (bid >> LS) * 4 + (threadIdx.x >> 6);
    int lane = threadIdx.x & 63;
    if (node >= n) return;
    int gid = lane >> 4;            // edge group 0..3
    int cl = lane & 15;             // col pair within slice
    int off = slice * 32 + cl * 2;

    float di = dinv[node];
    float self = di * di;
    ushort2 sv = *(const ushort2*)(h + (size_t)node * HC + off);
    float ax = (gid == 0) ? self * bf2f(sv.x) : 0.f;
    float ay = (gid == 0) ? self * bf2f(sv.y) : 0.f;

    int beg = row_ptr[node], end = row_ptr[node + 1];
    for (int base = beg; base < end; base += 64) {
        int k = base + lane;
        int mi = 0; float mc = 0.f;
        if (k < end) {
            mi = __builtin_nontemporal_load(csr_src + k);
            mc = __builtin_nontemporal_load(csr_coef + k);
        }
        int cnt = min(64, end - base);
        for (int j = 0; j < cnt; j += 16) {
            int e0 = j + gid, e1 = j + 4 + gid, e2 = j + 8 + gid, e3 = j + 12 + gid;
            int s0 = __shfl(mi, e0); float c0 = __shfl(mc, e0);
            int s1 = __shfl(mi, e1); float c1 = __shfl(mc, e1);
            int s2 = __shfl(mi, e2); float c2 = __shfl(mc, e2);
            int s3 = __shfl(mi, e3); float c3 = __shfl(mc, e3);
            ushort2 v0 = *(const ushort2*)(h + (size_t)s0 * HC + off);
            ushort2 v1 = *(const ushort2*)(h + (size_t)s1 * HC + off);
            ushort2 v2 = *(const ushort2*)(h + (size_t)s2 * HC + off);
            ushort2 v3 = *(const ushort2*)(h + (size_t)s3 * HC + off);
            ax += c0 * bf2f(v0.x) + c1 * bf2f(v1.x) + c2 * bf2f(v2.x) + c3 * bf2f(v3.x);
            ay += c0 * bf2f(v0.y) + c1 * bf2f(v1.y) + c2 * bf2f(v2.y) + c3 * bf2f(v3.y);
        }
    }
    // reduce the 4 edge-groups (same columns)
    ax += __shfl_xor(ax, 16); ax += __shfl_xor(ax, 32);
    ay += __shfl_xor(ay, 16); ay += __shfl_xor(ay, 32);
    if (gid == 0) {
        ushort2 o;
        o.x = f2bf(ax); o.y = f2bf(ay);
        *(ushort2*)(out + (size_t)node * HC + off) = o;
    }
}

// ---------------------------- register-A GEMM ------------------------------
// C[M, 0..ntiles*64) = act(A[M,K] @ Bt^T + bias) [+residual]
// Block: 4 waves x 32 rows = 128 rows; A frags in registers (read once);
// B frags straight from global (Wt is L2-resident). No LDS, no barriers.

template<int K, int RELU, int RES, int OUTF32>
__launch_bounds__(256)
__global__ void wgemm2(const unsigned short* __restrict__ A,
                       const unsigned short* __restrict__ Bt,
                       const float* __restrict__ bias,
                       const unsigned short* __restrict__ residual,
                       void* __restrict__ Cout,
                       int M, int N, int ntiles) {
    constexpr int KK = K / 32;
    int tid = threadIdx.x;
    int wave = tid >> 6, lane = tid & 63;
    int r = lane & 15, q = lane >> 4;
    int mr = blockIdx.y * 128 + wave * 32;
    int nbase = blockIdx.x * ntiles * 64;

    short8 a[2][KK];
    #pragma unroll
    for (int mi = 0; mi < 2; mi++) {
        int arow = mr + mi * 16 + r;
        bool ok = arow < M;
        const unsigned short* ap = A + (size_t)(ok ? arow : 0) * K;
        #pragma unroll
        for (int kk = 0; kk < KK; kk++) {
            short8 v = *(const short8*)(ap + kk * 32 + q * 8);
            if (!ok) v = (short8){0, 0, 0, 0, 0, 0, 0, 0};
            a[mi][kk] = v;
        }
    }

    for (int t = 0; t < ntiles; t++) {
        int n0 = nbase + t * 64;
        f32x4 acc[2][4];
        #pragma unroll
        for (int mi = 0; mi < 2; mi++)
            #pragma unroll
            for (int j = 0; j < 4; j++) acc[mi][j] = (f32x4){0.f, 0.f, 0.f, 0.f};

        #pragma unroll
        for (int kk = 0; kk < KK; kk++) {
            short8 b[4];
            #pragma unroll
            for (int j = 0; j < 4; j++)
                b[j] = *(const short8*)(Bt + (size_t)(n0 + j * 16 + r) * K + kk * 32 + q * 8);
            #pragma unroll
            for (int mi = 0; mi < 2; mi++)
                #pragma unroll
                for (int j = 0; j < 4; j++)
                    acc[mi][j] = __builtin_amdgcn_mfma_f32_16x16x32_bf16(a[mi][kk], b[j], acc[mi][j], 0, 0, 0);
        }

        float bb[4];
        #pragma unroll
        for (int j = 0; j < 4; j++) bb[j] = bias[n0 + j * 16 + r];

        #pragma unroll
        for (int mi = 0; mi < 2; mi++) {
            #pragma unroll
            for (int p = 0; p < 4; p++) {
                int row = mr + mi * 16 + q * 4 + p;
                if (row < M) {
                    #pragma unroll
                    for (int j = 0; j < 4; j++) {
                        int col = n0 + j * 16 + r;
                        float v = acc[mi][j][p] + bb[j];
                        if (RELU) v = fmaxf(v, 0.f);
                        if (RES) v += bf2f(residual[(size_t)row * N + col]);
                        if (OUTF32) ((float*)Cout)[(size_t)row * N + col] = v;
                        else ((unsigned short*)Cout)[(size_t)row * N + col] = f2bf(v);
                    }
                }
            }
        }
    }
}

// ---------------------------- pool / LN ------------------------------------

__global__ void pool_kernel(const unsigned short* __restrict__ h, const int* __restrict__ batch,
                            unsigned short* __restrict__ g0, int n) {
    int g = blockIdx.x;
    __shared__ int s_lo, s_hi;
    if (threadIdx.x == 0) {
        int lo = 0, hi = n;
        while (lo < hi) { int mid = (lo + hi) >> 1; if (batch[mid] < g) lo = mid + 1; else hi = mid; }
        s_lo = lo;
        int lo2 = lo, hi2 = n;
        while (lo2 < hi2) { int mid = (lo2 + hi2) >> 1; if (batch[mid] < g + 1) lo2 = mid + 1; else hi2 = mid; }
        s_hi = lo2;
    }
    __syncthreads();
    int lo = s_lo, hi = s_hi;
    float acc = 0.f;
    for (int i = lo; i < hi; i++) acc += bf2f(h[(size_t)i * 256 + threadIdx.x]);
    float cntf = (float)(hi - lo);
    g0[(size_t)g * 256 + threadIdx.x] = f2bf(acc / fmaxf(cntf, 1.0f));
}

__launch_bounds__(256)
__global__ void ln_kernel(const float* __restrict__ g2, const float* __restrict__ gamma,
                          const float* __restrict__ beta, float* __restrict__ out, int rows) {
    int row = blockIdx.x * 4 + (threadIdx.x >> 6);
    int lane = threadIdx.x & 63;
    if (row >= rows) return;
    const float* r = g2 + (size_t)row * 768;
    float v[12];
    float s = 0.f, s2 = 0.f;
    #pragma unroll
    for (int j = 0; j < 12; j++) {
        v[j] = r[lane + 64 * j];
        s += v[j];
        s2 += v[j] * v[j];
    }
    #pragma unroll
    for (int off = 32; off > 0; off >>= 1) {
        s += __shfl_down(s, off);
        s2 += __shfl_down(s2, off);
    }
    s = __shfl(s, 0);
    s2 = __shfl(s2, 0);
    float mu = s * (1.0f / 768.0f);
    float var = s2 * (1.0f / 768.0f) - mu * mu;
    float inv = rsqrtf(var + 1e-5f);
    #pragma unroll
    for (int j = 0; j < 12; j++) {
        int c = lane + 64 * j;
        out[(size_t)row * 768 + c] = (v[j] - mu) * inv * gamma[c] + beta[c];
    }
}

// ---------------------------------------------------------------------------

extern "C" void kernel_launch(void* const* d_in, const int* in_sizes, int n_in,
                              void* d_out, int out_size, void* d_ws, size_t ws_size,
                              hipStream_t stream) {
    const float* x    = (const float*)d_in[0];
    const int* eidx   = (const int*)d_in[1];
    const int* batch  = (const int*)d_in[2];
    const float* W1   = (const float*)d_in[3];
    const float* b1   = (const float*)d_in[4];
    const float* W2   = (const float*)d_in[5];
    const float* b2   = (const float*)d_in[6];
    const float* W3   = (const float*)d_in[7];
    const float* b3   = (const float*)d_in[8];
    const float* P1   = (const float*)d_in[9];
    const float* pb1  = (const float*)d_in[10];
    const float* P2   = (const float*)d_in[11];
    const float* pb2  = (const float*)d_in[12];
    const float* ln_g = (const float*)d_in[13];
    const float* ln_b = (const float*)d_in[14];
    float* out = (float*)d_out;

    const int N = in_sizes[2];            // 50000
    const int E = in_sizes[1] / 2;        // 800000
    const int F_IN = in_sizes[0] / N;     // 128
    const int H = in_sizes[4];            // 256
    const int D = in_sizes[12];           // 768
    const int G = out_size / D;           // 1024
    const int NPAD = (N + 127) & ~127;

    const int* src = eidx;
    const int* dst = eidx + E;

    char* ws = (char*)d_ws;
    size_t off = 0;
    auto alloc = [&](size_t bytes) -> char* {
        char* p = ws + off;
        off = (off + bytes + 255) & ~(size_t)255;
        return p;
    };
    int*   cnt      = (int*)alloc((size_t)NPAD * 4);   // cnt & fill contiguous -> one memset
    int*   fill     = (int*)alloc((size_t)NPAD * 4);
    float* dinv     = (float*)alloc((size_t)NPAD * 4);
    int*   row_ptr  = (int*)alloc((size_t)(N + 1) * 4);
    int*   csr_src  = (int*)alloc((size_t)E * 4);
    float* csr_coef = (float*)alloc((size_t)E * 4);
    unsigned short* x_bf = (unsigned short*)alloc((size_t)N * F_IN * 2);
    unsigned short* Wt1  = (unsigned short*)alloc((size_t)F_IN * H * 2);
    unsigned short* Wt2  = (unsigned short*)alloc((size_t)H * H * 2);
    unsigned short* Wt3  = (unsigned short*)alloc((size_t)H * H * 2);
    unsigned short* Pt1  = (unsigned short*)alloc((size_t)H * H * 2);
    unsigned short* Pt2  = (unsigned short*)alloc((size_t)H * D * 2);
    unsigned short* s1   = (unsigned short*)alloc((size_t)N * F_IN * 2);  // Â x (128)
    unsigned short* sA   = (unsigned short*)alloc((size_t)N * H * 2);     // Â h (256)
    unsigned short* h1   = (unsigned short*)alloc((size_t)N * H * 2);
    unsigned short* h2   = (unsigned short*)alloc((size_t)N * H * 2);
    unsigned short* h3   = (unsigned short*)alloc((size_t)N * H * 2);
    unsigned short* g0b  = (unsigned short*)alloc((size_t)G * H * 2);
    unsigned short* g1b  = (unsigned short*)alloc((size_t)G * H * 2);
    float* g2 = (float*)alloc((size_t)G * D * 4);
    (void)ws_size; (void)n_in;

    // --- CSR build -----------------------------------------------------------
    hipMemsetAsync(cnt, 0, (size_t)2 * NPAD * 4, stream);
    count_kernel<<<(E + 255) / 256, 256, 0, stream>>>(dst, E, cnt);
    dinv_kernel<<<(N + 255) / 256, 256, 0, stream>>>(cnt, dinv, N);
    scan_kernel<<<1, 1024, 0, stream>>>(cnt, N, row_ptr);
    scatter_kernel<<<(E + 255) / 256, 256, 0, stream>>>(src, dst, E, row_ptr, fill, dinv,
                                                        csr_src, csr_coef);

    // --- conversions ---------------------------------------------------------
    convert_bf16_vec<<<(N * F_IN / 4 + 255) / 256, 256, 0, stream>>>(x, x_bf, N * F_IN / 4);
    {
        int tot = F_IN * H + 3 * H * H + H * D;
        convert_weights<<<(tot + 255) / 256, 256, 0, stream>>>(W1, W2, W3, P1, P2,
                                                               Wt1, Wt2, Wt3, Pt1, Pt2,
                                                               F_IN, H, D);
    }

    // --- GCN layers (aggregate-first) ---------------------------------------
    int chunks = (N + 3) / 4;
    int mtiles = (N + 127) / 128;

    // layer 1: s1 = Â x (128-dim, 4 slices), h1 = relu(s1 @ W1 + b1)
    aggregate_sliced<128, 2><<<chunks * 4, 256, 0, stream>>>(x_bf, row_ptr, csr_src, csr_coef, dinv, s1, N);
    wgemm2<128, 1, 0, 0><<<dim3(1, mtiles), 256, 0, stream>>>(s1, Wt1, b1, nullptr, h1, N, H, 4);

    // layer 2: sA = Â h1 (8 slices), h2 = relu(sA @ W2 + b2) + h1
    aggregate_sliced<256, 3><<<chunks * 8, 256, 0, stream>>>(h1, row_ptr, csr_src, csr_coef, dinv, sA, N);
    wgemm2<256, 1, 1, 0><<<dim3(1, mtiles), 256, 0, stream>>>(sA, Wt2, b2, h1, h2, N, H, 4);

    // layer 3: sA = Â h2, h3 = relu(sA @ W3 + b3) + h2
    aggregate_sliced<256, 3><<<chunks * 8, 256, 0, stream>>>(h2, row_ptr, csr_src, csr_coef, dinv, sA, N);
    wgemm2<256, 1, 1, 0><<<dim3(1, mtiles), 256, 0, stream>>>(sA, Wt3, b3, h2, h3, N, H, 4);

    // --- pool + MLP + LN -----------------------------------------------------
    pool_kernel<<<G, 256, 0, stream>>>(h3, batch, g0b, N);
    wgemm2<256, 1, 0, 0><<<dim3(4, G / 128), 256, 0, stream>>>(g0b, Pt1, pb1, nullptr, g1b, G, H, 1);
    wgemm2<256, 0, 0, 1><<<dim3(12, G / 128), 256, 0, stream>>>(g1b, Pt2, pb2, nullptr, g2, G, D, 1);
    ln_kernel<<<G / 4, 256, 0, stream>>>(g2, ln_g, ln_b, out, G);
}

// Round 6
// 549.523 us; speedup vs baseline: 1.3923x; 1.3923x over previous
//
#include <hip/hip_runtime.h>

// ---------------------------------------------------------------------------
// GraphEncoder round 6:
//  - aggregation reverted to R4's full-row gather (XCD slicing measurably
//    failed: FETCH unchanged at ~8x25.6MB), now TWO adjacent nodes per wave
//    interleaved -> 16 independent gathers in flight, amortized row_ptr/meta
//    latency, zero-coef padding instead of tails.
//  - wgemm2 (register-A, L2-resident-B, barrier-free) kept; grid.x=2 for
//    load balance (782 blocks vs 391).
// ---------------------------------------------------------------------------

typedef __attribute__((ext_vector_type(8))) short short8;
typedef __attribute__((ext_vector_type(4))) float f32x4;

__device__ __forceinline__ float bf2f(unsigned short s) {
    union { unsigned u; float f; } v;
    v.u = ((unsigned)s) << 16;
    return v.f;
}
__device__ __forceinline__ unsigned short f2bf(float f) {
    union { float f; unsigned u; } v;
    v.f = f;
    unsigned r = (v.u + 0x7FFFu + ((v.u >> 16) & 1u)) >> 16;
    return (unsigned short)r;
}

// ---------------------------- CSR build ------------------------------------

__global__ void count_kernel(const int* __restrict__ dst, int E, int* __restrict__ cnt) {
    int e = blockIdx.x * blockDim.x + threadIdx.x;
    if (e < E) atomicAdd(&cnt[dst[e]], 1);
}

__global__ void dinv_kernel(const int* __restrict__ cnt, float* __restrict__ dinv, int n) {
    int i = blockIdx.x * blockDim.x + threadIdx.x;
    if (i < n) dinv[i] = rsqrtf((float)cnt[i] + 1.0f);  // deg = in-degree + self loop
}

// Exclusive scan, 8 elems/thread, single 1024-thread block (8192/pass).
__global__ void scan_kernel(const int* __restrict__ cnt, int n, int* __restrict__ row_ptr) {
    __shared__ int wsum[16];
    __shared__ int s_base;
    int tid = threadIdx.x;
    int lane = tid & 63;
    int w = tid >> 6;
    if (tid == 0) s_base = 0;
    __syncthreads();
    for (int start = 0; start < n; start += 8192) {
        int i = start + tid * 8;
        int v[8];
        int s = 0;
        #pragma unroll
        for (int u = 0; u < 8; u++) {
            v[u] = (i + u < n) ? cnt[i + u] : 0;
            s += v[u];
        }
        int incl = s;
        #pragma unroll
        for (int off = 1; off < 64; off <<= 1) {
            int t = __shfl_up(incl, off);
            if (lane >= off) incl += t;
        }
        if (lane == 63) wsum[w] = incl;
        __syncthreads();
        int woff = 0;
        for (int j = 0; j < w; j++) woff += wsum[j];
        int excl = s_base + woff + incl - s;
        #pragma unroll
        for (int u = 0; u < 8; u++) {
            if (i + u < n) row_ptr[i + u] = excl;
            excl += v[u];
        }
        __syncthreads();
        if (tid == 1023) s_base = excl;
        __syncthreads();
    }
    if (threadIdx.x == 0) row_ptr[n] = s_base;
}

__global__ void scatter_kernel(const int* __restrict__ src, const int* __restrict__ dst, int E,
                               const int* __restrict__ row_ptr, int* __restrict__ fill,
                               const float* __restrict__ dinv, int* __restrict__ csr_src,
                               float* __restrict__ csr_coef) {
    int e = blockIdx.x * blockDim.x + threadIdx.x;
    if (e < E) {
        int d = dst[e], s = src[e];
        int pos = atomicAdd(&fill[d], 1);
        int idx = row_ptr[d] + pos;
        csr_src[idx] = s;
        csr_coef[idx] = dinv[s] * dinv[d];
    }
}

// ---------------------------- conversions ----------------------------------

__global__ void convert_bf16_vec(const float* __restrict__ in, unsigned short* __restrict__ out, int n4) {
    int i = blockIdx.x * blockDim.x + threadIdx.x;
    if (i < n4) {
        float4 v = ((const float4*)in)[i];
        ushort4 o;
        o.x = f2bf(v.x); o.y = f2bf(v.y); o.z = f2bf(v.z); o.w = f2bf(v.w);
        ((ushort4*)out)[i] = o;
    }
}

// All 5 weight matrices: W [K,N] fp32 -> Wt [N,K] bf16, one launch.
__global__ void convert_weights(const float* __restrict__ W1, const float* __restrict__ W2,
                                const float* __restrict__ W3, const float* __restrict__ P1,
                                const float* __restrict__ P2,
                                unsigned short* __restrict__ Wt1, unsigned short* __restrict__ Wt2,
                                unsigned short* __restrict__ Wt3, unsigned short* __restrict__ Pt1,
                                unsigned short* __restrict__ Pt2,
                                int F_IN, int H, int D) {
    int idx = blockIdx.x * blockDim.x + threadIdx.x;
    int n1 = F_IN * H, n2 = H * H, n5 = H * D;
    const float* W; unsigned short* O; int N;
    int t = idx;
    if (t < n1)            { W = W1; O = Wt1; N = H; }
    else if ((t -= n1) < n2) { W = W2; O = Wt2; N = H; }
    else if ((t -= n2) < n2) { W = W3; O = Wt3; N = H; }
    else if ((t -= n2) < n2) { W = P1; O = Pt1; N = H; }
    else if ((t -= n2) < n5) { W = P2; O = Pt2; N = D; }
    else return;
    int k = t / N, n = t - k * N;
    int K = (W == W1) ? F_IN : H;
    O[(size_t)n * K + k] = f2bf(W[t]);
}

// ---------------------------- aggregation ----------------------------------
// s[node] = sum_e coef*h[src_e] + dinv^2*h[node]   (pure, bf16 io)
// One wave per TWO ADJACENT nodes (CSR ranges contiguous). Metadata loaded
// lane-parallel, broadcast via __shfl; 8 gathers per node interleaved ->
// up to 16 independent loads in flight. Padded lanes carry (mi=0, mc=0):
// harmless zero-coef row-0 gathers, no scalar tails.

__launch_bounds__(256)
__global__ void aggregate2_256(const unsigned short* __restrict__ h,
                               const int* __restrict__ row_ptr,
                               const int* __restrict__ csr_src,
                               const float* __restrict__ csr_coef,
                               const float* __restrict__ dinv,
                               unsigned short* __restrict__ out, int n) {
    int wave = threadIdx.x >> 6, lane = threadIdx.x & 63;
    int nA = (blockIdx.x * 4 + wave) * 2;
    if (nA >= n) return;
    int nB = nA + 1;
    bool hasB = nB < n;

    float aA[4], aB[4] = {0.f, 0.f, 0.f, 0.f};
    {
        float d = dinv[nA]; float self = d * d;
        ushort4 sv = *(const ushort4*)(h + (size_t)nA * 256 + lane * 4);
        aA[0] = self * bf2f(sv.x); aA[1] = self * bf2f(sv.y);
        aA[2] = self * bf2f(sv.z); aA[3] = self * bf2f(sv.w);
    }
    if (hasB) {
        float d = dinv[nB]; float self = d * d;
        ushort4 sv = *(const ushort4*)(h + (size_t)nB * 256 + lane * 4);
        aB[0] = self * bf2f(sv.x); aB[1] = self * bf2f(sv.y);
        aB[2] = self * bf2f(sv.z); aB[3] = self * bf2f(sv.w);
    }

    int begA = row_ptr[nA];
    int endA = row_ptr[nA + 1];
    int endB = hasB ? row_ptr[nB + 1] : endA;
    int baseA = begA, baseB = endA;   // B's range starts where A's ends

    while (baseA < endA || baseB < endB) {
        int kA = baseA + lane, kB = baseB + lane;
        int miA = 0, miB = 0; float mcA = 0.f, mcB = 0.f;
        if (kA < endA) { miA = csr_src[kA]; mcA = csr_coef[kA]; }
        if (kB < endB) { miB = csr_src[kB]; mcB = csr_coef[kB]; }
        int cntA = min(64, max(0, endA - baseA));
        int cntB = min(64, max(0, endB - baseB));
        int cnt = max(cntA, cntB);
        for (int j = 0; j < cnt; j += 8) {
            bool doA = j < cntA, doB = j < cntB;
            int sA[8], sB[8]; float cA[8], cB[8]; ushort4 vA[8], vB[8];
            if (doA) {
                #pragma unroll
                for (int u = 0; u < 8; u++) { sA[u] = __shfl(miA, j + u); cA[u] = __shfl(mcA, j + u); }
                #pragma unroll
                for (int u = 0; u < 8; u++) vA[u] = *(const ushort4*)(h + (size_t)sA[u] * 256 + lane * 4);
            }
            if (doB) {
                #pragma unroll
                for (int u = 0; u < 8; u++) { sB[u] = __shfl(miB, j + u); cB[u] = __shfl(mcB, j + u); }
                #pragma unroll
                for (int u = 0; u < 8; u++) vB[u] = *(const ushort4*)(h + (size_t)sB[u] * 256 + lane * 4);
            }
            if (doA) {
                #pragma unroll
                for (int u = 0; u < 8; u++) {
                    aA[0] += cA[u] * bf2f(vA[u].x); aA[1] += cA[u] * bf2f(vA[u].y);
                    aA[2] += cA[u] * bf2f(vA[u].z); aA[3] += cA[u] * bf2f(vA[u].w);
                }
            }
            if (doB) {
                #pragma unroll
                for (int u = 0; u < 8; u++) {
                    aB[0] += cB[u] * bf2f(vB[u].x); aB[1] += cB[u] * bf2f(vB[u].y);
                    aB[2] += cB[u] * bf2f(vB[u].z); aB[3] += cB[u] * bf2f(vB[u].w);
                }
            }
        }
        baseA += 64; baseB += 64;
    }

    ushort4 o;
    o.x = f2bf(aA[0]); o.y = f2bf(aA[1]); o.z = f2bf(aA[2]); o.w = f2bf(aA[3]);
    *(ushort4*)(out + (size_t)nA * 256 + lane * 4) = o;
    if (hasB) {
        o.x = f2bf(aB[0]); o.y = f2bf(aB[1]); o.z = f2bf(aB[2]); o.w = f2bf(aB[3]);
        *(ushort4*)(out + (size_t)nB * 256 + lane * 4) = o;
    }
}

__launch_bounds__(256)
__global__ void aggregate2_128(const unsigned short* __restrict__ h,
                               const int* __restrict__ row_ptr,
                               const int* __restrict__ csr_src,
                               const float* __restrict__ csr_coef,
                               const float* __restrict__ dinv,
                               unsigned short* __restrict__ out, int n) {
    int wave = threadIdx.x >> 6, lane = threadIdx.x & 63;
    int nA = (blockIdx.x * 4 + wave) * 2;
    if (nA >= n) return;
    int nB = nA + 1;
    bool hasB = nB < n;

    float aA[2], aB[2] = {0.f, 0.f};
    {
        float d = dinv[nA]; float self = d * d;
        ushort2 sv = *(const ushort2*)(h + (size_t)nA * 128 + lane * 2);
        aA[0] = self * bf2f(sv.x); aA[1] = self * bf2f(sv.y);
    }
    if (hasB) {
        float d = dinv[nB]; float self = d * d;
        ushort2 sv = *(const ushort2*)(h + (size_t)nB * 128 + lane * 2);
        aB[0] = self * bf2f(sv.x); aB[1] = self * bf2f(sv.y);
    }

    int begA = row_ptr[nA];
    int endA = row_ptr[nA + 1];
    int endB = hasB ? row_ptr[nB + 1] : endA;
    int baseA = begA, baseB = endA;

    while (baseA < endA || baseB < endB) {
        int kA = baseA + lane, kB = baseB + lane;
        int miA = 0, miB = 0; float mcA = 0.f, mcB = 0.f;
        if (kA < endA) { miA = csr_src[kA]; mcA = csr_coef[kA]; }
        if (kB < endB) { miB = csr_src[kB]; mcB = csr_coef[kB]; }
        int cntA = min(64, max(0, endA - baseA));
        int cntB = min(64, max(0, endB - baseB));
        int cnt = max(cntA, cntB);
        for (int j = 0; j < cnt; j += 8) {
            bool doA = j < cntA, doB = j < cntB;
            int sA[8], sB[8]; float cA[8], cB[8]; ushort2 vA[8], vB[8];
            if (doA) {
                #pragma unroll
                for (int u = 0; u < 8; u++) { sA[u] = __shfl(miA, j + u); cA[u] = __shfl(mcA, j + u); }
                #pragma unroll
                for (int u = 0; u < 8; u++) vA[u] = *(const ushort2*)(h + (size_t)sA[u] * 128 + lane * 2);
            }
            if (doB) {
                #pragma unroll
                for (int u = 0; u < 8; u++) { sB[u] = __shfl(miB, j + u); cB[u] = __shfl(mcB, j + u); }
                #pragma unroll
                for (int u = 0; u < 8; u++) vB[u] = *(const ushort2*)(h + (size_t)sB[u] * 128 + lane * 2);
            }
            if (doA) {
                #pragma unroll
                for (int u = 0; u < 8; u++) { aA[0] += cA[u] * bf2f(vA[u].x); aA[1] += cA[u] * bf2f(vA[u].y); }
            }
            if (doB) {
                #pragma unroll
                for (int u = 0; u < 8; u++) { aB[0] += cB[u] * bf2f(vB[u].x); aB[1] += cB[u] * bf2f(vB[u].y); }
            }
        }
        baseA += 64; baseB += 64;
    }

    ushort2 o;
    o.x = f2bf(aA[0]); o.y = f2bf(aA[1]);
    *(ushort2*)(out + (size_t)nA * 128 + lane * 2) = o;
    if (hasB) {
        o.x = f2bf(aB[0]); o.y = f2bf(aB[1]);
        *(ushort2*)(out + (size_t)nB * 128 + lane * 2) = o;
    }
}

// ---------------------------- register-A GEMM ------------------------------
// C[M, tiles] = act(A[M,K] @ Bt^T + bias) [+residual]
// Block: 4 waves x 32 rows = 128 rows; A frags in registers (read once per
// block); B frags straight from global (Wt is L2-resident). No LDS/barriers.

template<int K, int RELU, int RES, int OUTF32>
__launch_bounds__(256)
__global__ void wgemm2(const unsigned short* __restrict__ A,
                       const unsigned short* __restrict__ Bt,
                       const float* __restrict__ bias,
                       const unsigned short* __restrict__ residual,
                       void* __restrict__ Cout,
                       int M, int N, int ntiles) {
    constexpr int KK = K / 32;
    int tid = threadIdx.x;
    int wave = tid >> 6, lane = tid & 63;
    int r = lane & 15, q = lane >> 4;
    int mr = blockIdx.y * 128 + wave * 32;
    int nbase = blockIdx.x * ntiles * 64;

    short8 a[2][KK];
    #pragma unroll
    for (int mi = 0; mi < 2; mi++) {
        int arow = mr + mi * 16 + r;
        bool ok = arow < M;
        const unsigned short* ap = A + (size_t)(ok ? arow : 0) * K;
        #pragma unroll
        for (int kk = 0; kk < KK; kk++) {
            short8 v = *(const short8*)(ap + kk * 32 + q * 8);
            if (!ok) v = (short8){0, 0, 0, 0, 0, 0, 0, 0};
            a[mi][kk] = v;
        }
    }

    for (int t = 0; t < ntiles; t++) {
        int n0 = nbase + t * 64;
        f32x4 acc[2][4];
        #pragma unroll
        for (int mi = 0; mi < 2; mi++)
            #pragma unroll
            for (int j = 0; j < 4; j++) acc[mi][j] = (f32x4){0.f, 0.f, 0.f, 0.f};

        #pragma unroll
        for (int kk = 0; kk < KK; kk++) {
            short8 b[4];
            #pragma unroll
            for (int j = 0; j < 4; j++)
                b[j] = *(const short8*)(Bt + (size_t)(n0 + j * 16 + r) * K + kk * 32 + q * 8);
            #pragma unroll
            for (int mi = 0; mi < 2; mi++)
                #pragma unroll
                for (int j = 0; j < 4; j++)
                    acc[mi][j] = __builtin_amdgcn_mfma_f32_16x16x32_bf16(a[mi][kk], b[j], acc[mi][j], 0, 0, 0);
        }

        float bb[4];
        #pragma unroll
        for (int j = 0; j < 4; j++) bb[j] = bias[n0 + j * 16 + r];

        #pragma unroll
        for (int mi = 0; mi < 2; mi++) {
            #pragma unroll
            for (int p = 0; p < 4; p++) {
                int row = mr + mi * 16 + q * 4 + p;
                if (row < M) {
                    #pragma unroll
                    for (int j = 0; j < 4; j++) {
                        int col = n0 + j * 16 + r;
                        float v = acc[mi][j][p] + bb[j];
                        if (RELU) v = fmaxf(v, 0.f);
                        if (RES) v += bf2f(residual[(size_t)row * N + col]);
                        if (OUTF32) ((float*)Cout)[(size_t)row * N + col] = v;
                        else ((unsigned short*)Cout)[(size_t)row * N + col] = f2bf(v);
                    }
                }
            }
        }
    }
}

// ---------------------------- pool / LN ------------------------------------

__global__ void pool_kernel(const unsigned short* __restrict__ h, const int* __restrict__ batch,
                            unsigned short* __restrict__ g0, int n) {
    int g = blockIdx.x;
    __shared__ int s_lo, s_hi;
    if (threadIdx.x == 0) {
        int lo = 0, hi = n;
        while (lo < hi) { int mid = (lo + hi) >> 1; if (batch[mid] < g) lo = mid + 1; else hi = mid; }
        s_lo = lo;
        int lo2 = lo, hi2 = n;
        while (lo2 < hi2) { int mid = (lo2 + hi2) >> 1; if (batch[mid] < g + 1) lo2 = mid + 1; else hi2 = mid; }
        s_hi = lo2;
    }
    __syncthreads();
    int lo = s_lo, hi = s_hi;
    float acc = 0.f;
    for (int i = lo; i < hi; i++) acc += bf2f(h[(size_t)i * 256 + threadIdx.x]);
    float cntf = (float)(hi - lo);
    g0[(size_t)g * 256 + threadIdx.x] = f2bf(acc / fmaxf(cntf, 1.0f));
}

__launch_bounds__(256)
__global__ void ln_kernel(const float* __restrict__ g2, const float* __restrict__ gamma,
                          const float* __restrict__ beta, float* __restrict__ out, int rows) {
    int row = blockIdx.x * 4 + (threadIdx.x >> 6);
    int lane = threadIdx.x & 63;
    if (row >= rows) return;
    const float* r = g2 + (size_t)row * 768;
    float v[12];
    float s = 0.f, s2 = 0.f;
    #pragma unroll
    for (int j = 0; j < 12; j++) {
        v[j] = r[lane + 64 * j];
        s += v[j];
        s2 += v[j] * v[j];
    }
    #pragma unroll
    for (int off = 32; off > 0; off >>= 1) {
        s += __shfl_down(s, off);
        s2 += __shfl_down(s2, off);
    }
    s = __shfl(s, 0);
    s2 = __shfl(s2, 0);
    float mu = s * (1.0f / 768.0f);
    float var = s2 * (1.0f / 768.0f) - mu * mu;
    float inv = rsqrtf(var + 1e-5f);
    #pragma unroll
    for (int j = 0; j < 12; j++) {
        int c = lane + 64 * j;
        out[(size_t)row * 768 + c] = (v[j] - mu) * inv * gamma[c] + beta[c];
    }
}

// ---------------------------------------------------------------------------

extern "C" void kernel_launch(void* const* d_in, const int* in_sizes, int n_in,
                              void* d_out, int out_size, void* d_ws, size_t ws_size,
                              hipStream_t stream) {
    const float* x    = (const float*)d_in[0];
    const int* eidx   = (const int*)d_in[1];
    const int* batch  = (const int*)d_in[2];
    const float* W1   = (const float*)d_in[3];
    const float* b1   = (const float*)d_in[4];
    const float* W2   = (const float*)d_in[5];
    const float* b2   = (const float*)d_in[6];
    const float* W3   = (const float*)d_in[7];
    const float* b3   = (const float*)d_in[8];
    const float* P1   = (const float*)d_in[9];
    const float* pb1  = (const float*)d_in[10];
    const float* P2   = (const float*)d_in[11];
    const float* pb2  = (const float*)d_in[12];
    const float* ln_g = (const float*)d_in[13];
    const float* ln_b = (const float*)d_in[14];
    float* out = (float*)d_out;

    const int N = in_sizes[2];            // 50000
    const int E = in_sizes[1] / 2;        // 800000
    const int F_IN = in_sizes[0] / N;     // 128
    const int H = in_sizes[4];            // 256
    const int D = in_sizes[12];           // 768
    const int G = out_size / D;           // 1024
    const int NPAD = (N + 127) & ~127;

    const int* src = eidx;
    const int* dst = eidx + E;

    char* ws = (char*)d_ws;
    size_t off = 0;
    auto alloc = [&](size_t bytes) -> char* {
        char* p = ws + off;
        off = (off + bytes + 255) & ~(size_t)255;
        return p;
    };
    int*   cnt      = (int*)alloc((size_t)NPAD * 4);   // cnt & fill contiguous -> one memset
    int*   fill     = (int*)alloc((size_t)NPAD * 4);
    float* dinv     = (float*)alloc((size_t)NPAD * 4);
    int*   row_ptr  = (int*)alloc((size_t)(N + 1) * 4);
    int*   csr_src  = (int*)alloc((size_t)E * 4);
    float* csr_coef = (float*)alloc((size_t)E * 4);
    unsigned short* x_bf = (unsigned short*)alloc((size_t)N * F_IN * 2);
    unsigned short* Wt1  = (unsigned short*)alloc((size_t)F_IN * H * 2);
    unsigned short* Wt2  = (unsigned short*)alloc((size_t)H * H * 2);
    unsigned short* Wt3  = (unsigned short*)alloc((size_t)H * H * 2);
    unsigned short* Pt1  = (unsigned short*)alloc((size_t)H * H * 2);
    unsigned short* Pt2  = (unsigned short*)alloc((size_t)H * D * 2);
    unsigned short* s1   = (unsigned short*)alloc((size_t)N * F_IN * 2);  // Â x (128)
    unsigned short* sA   = (unsigned short*)alloc((size_t)N * H * 2);     // Â h (256)
    unsigned short* h1   = (unsigned short*)alloc((size_t)N * H * 2);
    unsigned short* h2   = (unsigned short*)alloc((size_t)N * H * 2);
    unsigned short* h3   = (unsigned short*)alloc((size_t)N * H * 2);
    unsigned short* g0b  = (unsigned short*)alloc((size_t)G * H * 2);
    unsigned short* g1b  = (unsigned short*)alloc((size_t)G * H * 2);
    float* g2 = (float*)alloc((size_t)G * D * 4);
    (void)ws_size; (void)n_in;

    // --- CSR build -----------------------------------------------------------
    hipMemsetAsync(cnt, 0, (size_t)2 * NPAD * 4, stream);
    count_kernel<<<(E + 255) / 256, 256, 0, stream>>>(dst, E, cnt);
    dinv_kernel<<<(N + 255) / 256, 256, 0, stream>>>(cnt, dinv, N);
    scan_kernel<<<1, 1024, 0, stream>>>(cnt, N, row_ptr);
    scatter_kernel<<<(E + 255) / 256, 256, 0, stream>>>(src, dst, E, row_ptr, fill, dinv,
                                                        csr_src, csr_coef);

    // --- conversions ---------------------------------------------------------
    convert_bf16_vec<<<(N * F_IN / 4 + 255) / 256, 256, 0, stream>>>(x, x_bf, N * F_IN / 4);
    {
        int tot = F_IN * H + 3 * H * H + H * D;
        convert_weights<<<(tot + 255) / 256, 256, 0, stream>>>(W1, W2, W3, P1, P2,
                                                               Wt1, Wt2, Wt3, Pt1, Pt2,
                                                               F_IN, H, D);
    }

    // --- GCN layers (aggregate-first) ---------------------------------------
    int agg_blocks = (N + 7) / 8;   // 4 waves x 2 nodes per block
    int mtiles = (N + 127) / 128;

    // layer 1: s1 = Â x (128-dim), h1 = relu(s1 @ W1 + b1)
    aggregate2_128<<<agg_blocks, 256, 0, stream>>>(x_bf, row_ptr, csr_src, csr_coef, dinv, s1, N);
    wgemm2<128, 1, 0, 0><<<dim3(2, mtiles), 256, 0, stream>>>(s1, Wt1, b1, nullptr, h1, N, H, 2);

    // layer 2: sA = Â h1, h2 = relu(sA @ W2 + b2) + h1
    aggregate2_256<<<agg_blocks, 256, 0, stream>>>(h1, row_ptr, csr_src, csr_coef, dinv, sA, N);
    wgemm2<256, 1, 1, 0><<<dim3(2, mtiles), 256, 0, stream>>>(sA, Wt2, b2, h1, h2, N, H, 2);

    // layer 3: sA = Â h2, h3 = relu(sA @ W3 + b3) + h2
    aggregate2_256<<<agg_blocks, 256, 0, stream>>>(h2, row_ptr, csr_src, csr_coef, dinv, sA, N);
    wgemm2<256, 1, 1, 0><<<dim3(2, mtiles), 256, 0, stream>>>(sA, Wt3, b3, h2, h3, N, H, 2);

    // --- pool + MLP + LN -----------------------------------------------------
    pool_kernel<<<G, 256, 0, stream>>>(h3, batch, g0b, N);
    wgemm2<256, 1, 0, 0><<<dim3(4, G / 128), 256, 0, stream>>>(g0b, Pt1, pb1, nullptr, g1b, G, H, 1);
    wgemm2<256, 0, 0, 1><<<dim3(12, G / 128), 256, 0, stream>>>(g1b, Pt2, pb2, nullptr, g2, G, D, 1);
    ln_kernel<<<G / 4, 256, 0, stream>>>(g2, ln_g, ln_b, out, G);
}

// Round 7
// 493.915 us; speedup vs baseline: 1.5490x; 1.1126x over previous
//
#include <hip/hip_runtime.h>

// ---------------------------------------------------------------------------
// GraphEncoder round 7: consolidation of best-measured components.
//  - aggregator: R4's one-node-per-wave 8-unrolled gather (proven 58.7us,
//    hardware plateau for random 512B gathers) + int2 fused CSR metadata.
//  - wgemm3: register-A read-ONCE + LDS-staged B tiles (grid.x=2, ntiles=2).
//  - dinv fused into scan; 16 dispatches total.
// ---------------------------------------------------------------------------

typedef __attribute__((ext_vector_type(8))) short short8;
typedef __attribute__((ext_vector_type(4))) float f32x4;

__device__ __forceinline__ float bf2f(unsigned short s) {
    union { unsigned u; float f; } v;
    v.u = ((unsigned)s) << 16;
    return v.f;
}
__device__ __forceinline__ unsigned short f2bf(float f) {
    union { float f; unsigned u; } v;
    v.f = f;
    unsigned r = (v.u + 0x7FFFu + ((v.u >> 16) & 1u)) >> 16;
    return (unsigned short)r;
}

// ---------------------------- CSR build ------------------------------------

__global__ void count_kernel(const int* __restrict__ dst, int E, int* __restrict__ cnt) {
    int e = blockIdx.x * blockDim.x + threadIdx.x;
    if (e < E) atomicAdd(&cnt[dst[e]], 1);
}

// Exclusive scan (4 elems/thread, single block) + fused dinv = rsqrt(cnt+1).
__global__ void scan_kernel(const int* __restrict__ cnt, int n, int* __restrict__ row_ptr,
                            float* __restrict__ dinv) {
    __shared__ int wsum[16];
    __shared__ int s_base;
    int tid = threadIdx.x;
    int lane = tid & 63;
    int w = tid >> 6;
    if (tid == 0) s_base = 0;
    __syncthreads();
    for (int start = 0; start < n; start += 4096) {
        int i = start + tid * 4;
        int v0 = (i + 0 < n) ? cnt[i + 0] : 0;
        int v1 = (i + 1 < n) ? cnt[i + 1] : 0;
        int v2 = (i + 2 < n) ? cnt[i + 2] : 0;
        int v3 = (i + 3 < n) ? cnt[i + 3] : 0;
        if (i + 0 < n) dinv[i + 0] = rsqrtf((float)v0 + 1.0f);
        if (i + 1 < n) dinv[i + 1] = rsqrtf((float)v1 + 1.0f);
        if (i + 2 < n) dinv[i + 2] = rsqrtf((float)v2 + 1.0f);
        if (i + 3 < n) dinv[i + 3] = rsqrtf((float)v3 + 1.0f);
        int s = v0 + v1 + v2 + v3;
        int incl = s;
        #pragma unroll
        for (int off = 1; off < 64; off <<= 1) {
            int t = __shfl_up(incl, off);
            if (lane >= off) incl += t;
        }
        if (lane == 63) wsum[w] = incl;
        __syncthreads();
        int woff = 0;
        for (int j = 0; j < w; j++) woff += wsum[j];
        int excl = s_base + woff + incl - s;
        if (i + 0 < n) row_ptr[i + 0] = excl;
        if (i + 1 < n) row_ptr[i + 1] = excl + v0;
        if (i + 2 < n) row_ptr[i + 2] = excl + v0 + v1;
        if (i + 3 < n) row_ptr[i + 3] = excl + v0 + v1 + v2;
        __syncthreads();
        if (tid == 1023) s_base = excl + v0 + v1 + v2 + v3;
        __syncthreads();
    }
    if (threadIdx.x == 0) row_ptr[n] = s_base;
}

__global__ void scatter_kernel(const int* __restrict__ src, const int* __restrict__ dst, int E,
                               const int* __restrict__ row_ptr, int* __restrict__ fill,
                               const float* __restrict__ dinv, int2* __restrict__ csr) {
    int e = blockIdx.x * blockDim.x + threadIdx.x;
    if (e < E) {
        int d = dst[e], s = src[e];
        int pos = atomicAdd(&fill[d], 1);
        float coef = dinv[s] * dinv[d];
        csr[row_ptr[d] + pos] = make_int2(s, __float_as_int(coef));
    }
}

// ---------------------------- conversions ----------------------------------

__global__ void convert_bf16_vec(const float* __restrict__ in, unsigned short* __restrict__ out, int n4) {
    int i = blockIdx.x * blockDim.x + threadIdx.x;
    if (i < n4) {
        float4 v = ((const float4*)in)[i];
        ushort4 o;
        o.x = f2bf(v.x); o.y = f2bf(v.y); o.z = f2bf(v.z); o.w = f2bf(v.w);
        ((ushort4*)out)[i] = o;
    }
}

// All 5 weight matrices: W [K,N] fp32 -> Wt [N,K] bf16, one launch.
__global__ void convert_weights(const float* __restrict__ W1, const float* __restrict__ W2,
                                const float* __restrict__ W3, const float* __restrict__ P1,
                                const float* __restrict__ P2,
                                unsigned short* __restrict__ Wt1, unsigned short* __restrict__ Wt2,
                                unsigned short* __restrict__ Wt3, unsigned short* __restrict__ Pt1,
                                unsigned short* __restrict__ Pt2,
                                int F_IN, int H, int D) {
    int idx = blockIdx.x * blockDim.x + threadIdx.x;
    int n1 = F_IN * H, n2 = H * H, n5 = H * D;
    const float* W; unsigned short* O; int N;
    int t = idx;
    if (t < n1)            { W = W1; O = Wt1; N = H; }
    else if ((t -= n1) < n2) { W = W2; O = Wt2; N = H; }
    else if ((t -= n2) < n2) { W = W3; O = Wt3; N = H; }
    else if ((t -= n2) < n2) { W = P1; O = Pt1; N = H; }
    else if ((t -= n2) < n5) { W = P2; O = Pt2; N = D; }
    else return;
    int k = t / N, n = t - k * N;
    int K = (W == W1) ? F_IN : H;
    O[(size_t)n * K + k] = f2bf(W[t]);
}

// ---------------------------- aggregation ----------------------------------
// s[node] = sum_e coef*h[src_e] + dinv^2*h[node]   (pure, bf16 io)
// One wave per node; (src,coef) packed int2, loaded lane-parallel, broadcast
// via __shfl; 8 gathers unrolled -> 8 independent 512B loads in flight.

__launch_bounds__(256)
__global__ void aggregate256(const unsigned short* __restrict__ h,
                             const int* __restrict__ row_ptr,
                             const int2* __restrict__ csr,
                             const float* __restrict__ dinv,
                             unsigned short* __restrict__ out, int n) {
    int node = blockIdx.x * 4 + (threadIdx.x >> 6);
    int lane = threadIdx.x & 63;
    if (node >= n) return;
    float di = dinv[node];
    float self = di * di;
    ushort4 sv = *(const ushort4*)(h + (size_t)node * 256 + lane * 4);
    float ax = self * bf2f(sv.x), ay = self * bf2f(sv.y);
    float az = self * bf2f(sv.z), aw = self * bf2f(sv.w);
    int beg = row_ptr[node], end = row_ptr[node + 1];
    for (int base = beg; base < end; base += 64) {
        int k = base + lane;
        int mi = 0; float mc = 0.f;
        if (k < end) { int2 m = csr[k]; mi = m.x; mc = __int_as_float(m.y); }
        int cnt = min(64, end - base);
        int j = 0;
        for (; j + 8 <= cnt; j += 8) {
            int ss[8]; float cc[8]; ushort4 vv[8];
            #pragma unroll
            for (int u = 0; u < 8; u++) { ss[u] = __shfl(mi, j + u); cc[u] = __shfl(mc, j + u); }
            #pragma unroll
            for (int u = 0; u < 8; u++) vv[u] = *(const ushort4*)(h + (size_t)ss[u] * 256 + lane * 4);
            #pragma unroll
            for (int u = 0; u < 8; u++) {
                ax += cc[u] * bf2f(vv[u].x); ay += cc[u] * bf2f(vv[u].y);
                az += cc[u] * bf2f(vv[u].z); aw += cc[u] * bf2f(vv[u].w);
            }
        }
        for (; j < cnt; j++) {
            int s = __shfl(mi, j); float c = __shfl(mc, j);
            ushort4 v = *(const ushort4*)(h + (size_t)s * 256 + lane * 4);
            ax += c * bf2f(v.x); ay += c * bf2f(v.y);
            az += c * bf2f(v.z); aw += c * bf2f(v.w);
        }
    }
    ushort4 o;
    o.x = f2bf(ax); o.y = f2bf(ay); o.z = f2bf(az); o.w = f2bf(aw);
    *(ushort4*)(out + (size_t)node * 256 + lane * 4) = o;
}

__launch_bounds__(256)
__global__ void aggregate128(const unsigned short* __restrict__ h,
                             const int* __restrict__ row_ptr,
                             const int2* __restrict__ csr,
                             const float* __restrict__ dinv,
                             unsigned short* __restrict__ out, int n) {
    int node = blockIdx.x * 4 + (threadIdx.x >> 6);
    int lane = threadIdx.x & 63;
    if (node >= n) return;
    float di = dinv[node];
    float self = di * di;
    ushort2 sv = *(const ushort2*)(h + (size_t)node * 128 + lane * 2);
    float ax = self * bf2f(sv.x), ay = self * bf2f(sv.y);
    int beg = row_ptr[node], end = row_ptr[node + 1];
    for (int base = beg; base < end; base += 64) {
        int k = base + lane;
        int mi = 0; float mc = 0.f;
        if (k < end) { int2 m = csr[k]; mi = m.x; mc = __int_as_float(m.y); }
        int cnt = min(64, end - base);
        int j = 0;
        for (; j + 8 <= cnt; j += 8) {
            int ss[8]; float cc[8]; ushort2 vv[8];
            #pragma unroll
            for (int u = 0; u < 8; u++) { ss[u] = __shfl(mi, j + u); cc[u] = __shfl(mc, j + u); }
            #pragma unroll
            for (int u = 0; u < 8; u++) vv[u] = *(const ushort2*)(h + (size_t)ss[u] * 128 + lane * 2);
            #pragma unroll
            for (int u = 0; u < 8; u++) {
                ax += cc[u] * bf2f(vv[u].x); ay += cc[u] * bf2f(vv[u].y);
            }
        }
        for (; j < cnt; j++) {
            int s = __shfl(mi, j); float c = __shfl(mc, j);
            ushort2 v = *(const ushort2*)(h + (size_t)s * 128 + lane * 2);
            ax += c * bf2f(v.x); ay += c * bf2f(v.y);
        }
    }
    ushort2 o;
    o.x = f2bf(ax); o.y = f2bf(ay);
    *(ushort2*)(out + (size_t)node * 128 + lane * 2) = o;
}

// ---------------------------- wgemm3 ---------------------------------------
// C[M, cols] = act(A[M,K] @ Bt[N,K]^T + bias) [+residual]
// 4 waves x 32 rows = 128 rows/block. A frags in registers, read ONCE.
// Per 64-col tile: B strip staged to LDS (coalesced), 2 barriers, MFMA loop.

template<int K, int RELU, int RES, int OUTF32>
__launch_bounds__(256)
__global__ void wgemm3(const unsigned short* __restrict__ A,
                       const unsigned short* __restrict__ Bt,
                       const float* __restrict__ bias,
                       const unsigned short* __restrict__ residual,
                       void* __restrict__ Cout,
                       int M, int N, int ntiles) {
    constexpr int KK = K / 32;
    constexpr int S = K + 8;           // LDS stride in shorts (keeps 16B align)
    constexpr int CPR = K / 8;         // short8 chunks per B row
    __shared__ unsigned short Bs[64 * S];

    int tid = threadIdx.x;
    int wave = tid >> 6, lane = tid & 63;
    int r = lane & 15, q = lane >> 4;
    int mr = blockIdx.y * 128 + wave * 32;
    int nbase = blockIdx.x * ntiles * 64;

    // A fragments: read once per block.
    short8 a[2][KK];
    #pragma unroll
    for (int mi = 0; mi < 2; mi++) {
        int arow = mr + mi * 16 + r;
        bool ok = arow < M;
        const unsigned short* ap = A + (size_t)(ok ? arow : 0) * K;
        #pragma unroll
        for (int kk = 0; kk < KK; kk++) {
            short8 v = *(const short8*)(ap + kk * 32 + q * 8);
            if (!ok) v = (short8){0, 0, 0, 0, 0, 0, 0, 0};
            a[mi][kk] = v;
        }
    }

    for (int t = 0; t < ntiles; t++) {
        int n0 = nbase + t * 64;
        if (t > 0) __syncthreads();    // previous tile's reads done
        #pragma unroll
        for (int pass = 0; pass < 64 * CPR / 256; pass++) {
            int f = pass * 256 + tid;
            int row = f / CPR, ch = f % CPR;
            *(short8*)&Bs[row * S + ch * 8] =
                *(const short8*)(Bt + (size_t)(n0 + row) * K + ch * 8);
        }
        __syncthreads();

        f32x4 acc[2][4];
        #pragma unroll
        for (int mi = 0; mi < 2; mi++)
            #pragma unroll
            for (int j = 0; j < 4; j++) acc[mi][j] = (f32x4){0.f, 0.f, 0.f, 0.f};

        #pragma unroll
        for (int kk = 0; kk < KK; kk++) {
            short8 b[4];
            #pragma unroll
            for (int j = 0; j < 4; j++)
                b[j] = *(short8*)&Bs[(j * 16 + r) * S + kk * 32 + q * 8];
            #pragma unroll
            for (int mi = 0; mi < 2; mi++)
                #pragma unroll
                for (int j = 0; j < 4; j++)
                    acc[mi][j] = __builtin_amdgcn_mfma_f32_16x16x32_bf16(a[mi][kk], b[j], acc[mi][j], 0, 0, 0);
        }

        float bb[4];
        #pragma unroll
        for (int j = 0; j < 4; j++) bb[j] = bias[n0 + j * 16 + r];

        #pragma unroll
        for (int mi = 0; mi < 2; mi++) {
            #pragma unroll
            for (int p = 0; p < 4; p++) {
                int row = mr + mi * 16 + q * 4 + p;
                if (row < M) {
                    #pragma unroll
                    for (int j = 0; j < 4; j++) {
                        int col = n0 + j * 16 + r;
                        float v = acc[mi][j][p] + bb[j];
                        if (RELU) v = fmaxf(v, 0.f);
                        if (RES) v += bf2f(residual[(size_t)row * N + col]);
                        if (OUTF32) ((float*)Cout)[(size_t)row * N + col] = v;
                        else ((unsigned short*)Cout)[(size_t)row * N + col] = f2bf(v);
                    }
                }
            }
        }
    }
}

// ---------------------------- pool / LN ------------------------------------

__global__ void pool_kernel(const unsigned short* __restrict__ h, const int* __restrict__ batch,
                            unsigned short* __restrict__ g0, int n) {
    int g = blockIdx.x;
    __shared__ int s_lo, s_hi;
    if (threadIdx.x == 0) {
        int lo = 0, hi = n;
        while (lo < hi) { int mid = (lo + hi) >> 1; if (batch[mid] < g) lo = mid + 1; else hi = mid; }
        s_lo = lo;
        int lo2 = lo, hi2 = n;
        while (lo2 < hi2) { int mid = (lo2 + hi2) >> 1; if (batch[mid] < g + 1) lo2 = mid + 1; else hi2 = mid; }
        s_hi = lo2;
    }
    __syncthreads();
    int lo = s_lo, hi = s_hi;
    float acc = 0.f;
    for (int i = lo; i < hi; i++) acc += bf2f(h[(size_t)i * 256 + threadIdx.x]);
    float cntf = (float)(hi - lo);
    g0[(size_t)g * 256 + threadIdx.x] = f2bf(acc / fmaxf(cntf, 1.0f));
}

__launch_bounds__(256)
__global__ void ln_kernel(const float* __restrict__ g2, const float* __restrict__ gamma,
                          const float* __restrict__ beta, float* __restrict__ out, int rows) {
    int row = blockIdx.x * 4 + (threadIdx.x >> 6);
    int lane = threadIdx.x & 63;
    if (row >= rows) return;
    const float* r = g2 + (size_t)row * 768;
    float v[12];
    float s = 0.f, s2 = 0.f;
    #pragma unroll
    for (int j = 0; j < 12; j++) {
        v[j] = r[lane + 64 * j];
        s += v[j];
        s2 += v[j] * v[j];
    }
    #pragma unroll
    for (int off = 32; off > 0; off >>= 1) {
        s += __shfl_down(s, off);
        s2 += __shfl_down(s2, off);
    }
    s = __shfl(s, 0);
    s2 = __shfl(s2, 0);
    float mu = s * (1.0f / 768.0f);
    float var = s2 * (1.0f / 768.0f) - mu * mu;
    float inv = rsqrtf(var + 1e-5f);
    #pragma unroll
    for (int j = 0; j < 12; j++) {
        int c = lane + 64 * j;
        out[(size_t)row * 768 + c] = (v[j] - mu) * inv * gamma[c] + beta[c];
    }
}

// ---------------------------------------------------------------------------

extern "C" void kernel_launch(void* const* d_in, const int* in_sizes, int n_in,
                              void* d_out, int out_size, void* d_ws, size_t ws_size,
                              hipStream_t stream) {
    const float* x    = (const float*)d_in[0];
    const int* eidx   = (const int*)d_in[1];
    const int* batch  = (const int*)d_in[2];
    const float* W1   = (const float*)d_in[3];
    const float* b1   = (const float*)d_in[4];
    const float* W2   = (const float*)d_in[5];
    const float* b2   = (const float*)d_in[6];
    const float* W3   = (const float*)d_in[7];
    const float* b3   = (const float*)d_in[8];
    const float* P1   = (const float*)d_in[9];
    const float* pb1  = (const float*)d_in[10];
    const float* P2   = (const float*)d_in[11];
    const float* pb2  = (const float*)d_in[12];
    const float* ln_g = (const float*)d_in[13];
    const float* ln_b = (const float*)d_in[14];
    float* out = (float*)d_out;

    const int N = in_sizes[2];            // 50000
    const int E = in_sizes[1] / 2;        // 800000
    const int F_IN = in_sizes[0] / N;     // 128
    const int H = in_sizes[4];            // 256
    const int D = in_sizes[12];           // 768
    const int G = out_size / D;           // 1024
    const int NPAD = (N + 127) & ~127;

    const int* src = eidx;
    const int* dst = eidx + E;

    char* ws = (char*)d_ws;
    size_t off = 0;
    auto alloc = [&](size_t bytes) -> char* {
        char* p = ws + off;
        off = (off + bytes + 255) & ~(size_t)255;
        return p;
    };
    int*   cnt      = (int*)alloc((size_t)NPAD * 4);   // cnt & fill contiguous -> one memset
    int*   fill     = (int*)alloc((size_t)NPAD * 4);
    float* dinv     = (float*)alloc((size_t)NPAD * 4);
    int*   row_ptr  = (int*)alloc((size_t)(N + 1) * 4);
    int2*  csr      = (int2*)alloc((size_t)E * 8);
    unsigned short* x_bf = (unsigned short*)alloc((size_t)N * F_IN * 2);
    unsigned short* Wt1  = (unsigned short*)alloc((size_t)F_IN * H * 2);
    unsigned short* Wt2  = (unsigned short*)alloc((size_t)H * H * 2);
    unsigned short* Wt3  = (unsigned short*)alloc((size_t)H * H * 2);
    unsigned short* Pt1  = (unsigned short*)alloc((size_t)H * H * 2);
    unsigned short* Pt2  = (unsigned short*)alloc((size_t)H * D * 2);
    unsigned short* s1   = (unsigned short*)alloc((size_t)N * F_IN * 2);  // Â x (128)
    unsigned short* sA   = (unsigned short*)alloc((size_t)N * H * 2);     // Â h (256)
    unsigned short* h1   = (unsigned short*)alloc((size_t)N * H * 2);
    unsigned short* h2   = (unsigned short*)alloc((size_t)N * H * 2);
    unsigned short* h3   = (unsigned short*)alloc((size_t)N * H * 2);
    unsigned short* g0b  = (unsigned short*)alloc((size_t)G * H * 2);
    unsigned short* g1b  = (unsigned short*)alloc((size_t)G * H * 2);
    float* g2 = (float*)alloc((size_t)G * D * 4);
    (void)ws_size; (void)n_in;

    // --- CSR build -----------------------------------------------------------
    hipMemsetAsync(cnt, 0, (size_t)2 * NPAD * 4, stream);
    count_kernel<<<(E + 255) / 256, 256, 0, stream>>>(dst, E, cnt);
    scan_kernel<<<1, 1024, 0, stream>>>(cnt, N, row_ptr, dinv);
    scatter_kernel<<<(E + 255) / 256, 256, 0, stream>>>(src, dst, E, row_ptr, fill, dinv, csr);

    // --- conversions ---------------------------------------------------------
    convert_bf16_vec<<<(N * F_IN / 4 + 255) / 256, 256, 0, stream>>>(x, x_bf, N * F_IN / 4);
    {
        int tot = F_IN * H + 3 * H * H + H * D;
        convert_weights<<<(tot + 255) / 256, 256, 0, stream>>>(W1, W2, W3, P1, P2,
                                                               Wt1, Wt2, Wt3, Pt1, Pt2,
                                                               F_IN, H, D);
    }

    // --- GCN layers (aggregate-first) ---------------------------------------
    int agg_grid = (N + 3) / 4;
    int mtiles = (N + 127) / 128;

    // layer 1: s1 = Â x (128-dim), h1 = relu(s1 @ W1 + b1)
    aggregate128<<<agg_grid, 256, 0, stream>>>(x_bf, row_ptr, csr, dinv, s1, N);
    wgemm3<128, 1, 0, 0><<<dim3(2, mtiles), 256, 0, stream>>>(s1, Wt1, b1, nullptr, h1, N, H, 2);

    // layer 2: sA = Â h1, h2 = relu(sA @ W2 + b2) + h1
    aggregate256<<<agg_grid, 256, 0, stream>>>(h1, row_ptr, csr, dinv, sA, N);
    wgemm3<256, 1, 1, 0><<<dim3(2, mtiles), 256, 0, stream>>>(sA, Wt2, b2, h1, h2, N, H, 2);

    // layer 3: sA = Â h2, h3 = relu(sA @ W3 + b3) + h2
    aggregate256<<<agg_grid, 256, 0, stream>>>(h2, row_ptr, csr, dinv, sA, N);
    wgemm3<256, 1, 1, 0><<<dim3(2, mtiles), 256, 0, stream>>>(sA, Wt3, b3, h2, h3, N, H, 2);

    // --- pool + MLP + LN -----------------------------------------------------
    pool_kernel<<<G, 256, 0, stream>>>(h3, batch, g0b, N);
    wgemm3<256, 1, 0, 0><<<dim3(2, G / 128), 256, 0, stream>>>(g0b, Pt1, pb1, nullptr, g1b, G, H, 2);
    wgemm3<256, 0, 0, 1><<<dim3(4, G / 128), 256, 0, stream>>>(g1b, Pt2, pb2, nullptr, g2, G, D, 3);
    ln_kernel<<<G / 4, 256, 0, stream>>>(g2, ln_g, ln_b, out, G);
}

// Round 8
// 474.433 us; speedup vs baseline: 1.6126x; 1.0411x over previous
//
#include <hip/hip_runtime.h>

// ---------------------------------------------------------------------------
// GraphEncoder round 8: coefficient-free aggregation via dinv folding.
//   h-space -> ĥ-space: ĥ = dinv*h stored by GEMM epilogues; aggregator is a
//   PURE SUM over src rows (csr = src only, 4B/edge), paired-edge 16B gathers.
//   GEMM epilogue: v = relu(di*acc + b) [+ ĥprev/di]; store di*v (or v at L3).
//   Multi-block scan; wide MLP grids; wave-per-graph pool.
// ---------------------------------------------------------------------------

typedef __attribute__((ext_vector_type(8))) short short8;
typedef __attribute__((ext_vector_type(4))) float f32x4;

__device__ __forceinline__ float bf2f(unsigned short s) {
    union { unsigned u; float f; } v;
    v.u = ((unsigned)s) << 16;
    return v.f;
}
__device__ __forceinline__ unsigned short f2bf(float f) {
    union { float f; unsigned u; } v;
    v.f = f;
    unsigned r = (v.u + 0x7FFFu + ((v.u >> 16) & 1u)) >> 16;
    return (unsigned short)r;
}

// ---------------------------- CSR build ------------------------------------

__global__ void count_kernel(const int* __restrict__ dst, int E, int* __restrict__ cnt) {
    int e = blockIdx.x * blockDim.x + threadIdx.x;
    if (e < E) atomicAdd(&cnt[dst[e]], 1);
}

// Phase A: per-block sums of cnt (512/block) + dinv.
__global__ void scanA(const int* __restrict__ cnt, int n, int* __restrict__ bsum,
                      float* __restrict__ dinv) {
    int tid = threadIdx.x, lane = tid & 63, w = tid >> 6;
    int i = blockIdx.x * 512 + tid;
    int v = (i < n) ? cnt[i] : 0;
    if (i < n) dinv[i] = rsqrtf((float)v + 1.0f);
    int s = v;
    #pragma unroll
    for (int off = 1; off < 64; off <<= 1) s += __shfl_xor(s, off);
    __shared__ int ws[8];
    if (lane == 0) ws[w] = s;
    __syncthreads();
    if (tid == 0) {
        int t = 0;
        #pragma unroll
        for (int j = 0; j < 8; j++) t += ws[j];
        bsum[blockIdx.x] = t;
    }
}

// Phase B: serial exclusive scan of nb block sums (nb <= 128); writes
// row_ptr[n]=E and zeroes the dummy gather rows of xh/hh1/hh2.
__global__ void scanB(int* __restrict__ bsum, int nb, int n, int* __restrict__ row_ptr,
                      unsigned short* __restrict__ xh_zrow,
                      unsigned short* __restrict__ h1_zrow,
                      unsigned short* __restrict__ h2_zrow) {
    int tid = threadIdx.x;
    for (int c = tid; c < 128; c += 256) xh_zrow[c] = 0;
    for (int c = tid; c < 256; c += 256) { h1_zrow[c] = 0; h2_zrow[c] = 0; }
    if (tid == 0) {
        int run = 0;
        for (int b = 0; b < nb; b++) { int t = bsum[b]; bsum[b] = run; run += t; }
        row_ptr[n] = run;
    }
}

// Phase C: block-local exclusive scan + block offset -> row_ptr.
__global__ void scanC(const int* __restrict__ cnt, int n, const int* __restrict__ bsum,
                      int* __restrict__ row_ptr) {
    int tid = threadIdx.x, lane = tid & 63, w = tid >> 6;
    int i = blockIdx.x * 512 + tid;
    int v = (i < n) ? cnt[i] : 0;
    int incl = v;
    #pragma unroll
    for (int off = 1; off < 64; off <<= 1) {
        int t = __shfl_up(incl, off);
        if (lane >= off) incl += t;
    }
    __shared__ int ws[8];
    if (lane == 63) ws[w] = incl;
    __syncthreads();
    int woff = 0;
    for (int j = 0; j < w; j++) woff += ws[j];
    if (i < n) row_ptr[i] = bsum[blockIdx.x] + woff + incl - v;
}

__global__ void scatter_kernel(const int* __restrict__ src, const int* __restrict__ dst, int E,
                               const int* __restrict__ row_ptr, int* __restrict__ fill,
                               int* __restrict__ csr) {
    int e = blockIdx.x * blockDim.x + threadIdx.x;
    if (e < E) {
        int d = dst[e];
        int pos = atomicAdd(&fill[d], 1);
        csr[row_ptr[d] + pos] = src[e];
    }
}

// ---------------------------- conversions ----------------------------------

// x̂ = dinv[row] * x, fp32 -> bf16. (row = float4-index >> 5 for F_IN=128)
__global__ void convert_x(const float* __restrict__ in, const float* __restrict__ dinv,
                          unsigned short* __restrict__ out, int n4, int l2fq) {
    int i = blockIdx.x * blockDim.x + threadIdx.x;
    if (i < n4) {
        float di = dinv[i >> l2fq];
        float4 v = ((const float4*)in)[i];
        ushort4 o;
        o.x = f2bf(di * v.x); o.y = f2bf(di * v.y);
        o.z = f2bf(di * v.z); o.w = f2bf(di * v.w);
        ((ushort4*)out)[i] = o;
    }
}

// All 5 weight matrices: W [K,N] fp32 -> Wt [N,K] bf16, one launch.
__global__ void convert_weights(const float* __restrict__ W1, const float* __restrict__ W2,
                                const float* __restrict__ W3, const float* __restrict__ P1,
                                const float* __restrict__ P2,
                                unsigned short* __restrict__ Wt1, unsigned short* __restrict__ Wt2,
                                unsigned short* __restrict__ Wt3, unsigned short* __restrict__ Pt1,
                                unsigned short* __restrict__ Pt2,
                                int F_IN, int H, int D) {
    int idx = blockIdx.x * blockDim.x + threadIdx.x;
    int n1 = F_IN * H, n2 = H * H, n5 = H * D;
    const float* W; unsigned short* O; int N;
    int t = idx;
    if (t < n1)            { W = W1; O = Wt1; N = H; }
    else if ((t -= n1) < n2) { W = W2; O = Wt2; N = H; }
    else if ((t -= n2) < n2) { W = W3; O = Wt3; N = H; }
    else if ((t -= n2) < n2) { W = P1; O = Pt1; N = H; }
    else if ((t -= n2) < n5) { W = P2; O = Pt2; N = D; }
    else return;
    int k = t / N, n = t - k * N;
    int K = (W == W1) ? F_IN : H;
    O[(size_t)n * K + k] = f2bf(W[t]);
}

// ---------------------------- aggregation (pure sum) -----------------------
// t[node] = ĥ[node] + sum_e ĥ[src_e].  h has a zeroed dummy row `zrow` for
// tail padding.  HC=256: half-wave x ushort8 covers a row, 2 edges/instr.

__launch_bounds__(256)
__global__ void aggregate256(const unsigned short* __restrict__ h,
                             const int* __restrict__ row_ptr,
                             const int* __restrict__ csr,
                             unsigned short* __restrict__ out, int n, int zrow) {
    int node = blockIdx.x * 4 + (threadIdx.x >> 6);
    int lane = threadIdx.x & 63;
    if (node >= n) return;
    int half = lane >> 5;          // edge of the pair
    int cl = lane & 31;            // 8-col chunk
    float acc[8] = {0, 0, 0, 0, 0, 0, 0, 0};
    if (half == 0) {
        short8 sv = *(const short8*)(h + (size_t)node * 256 + cl * 8);
        #pragma unroll
        for (int c = 0; c < 8; c++) acc[c] = bf2f((unsigned short)sv[c]);
    }
    int beg = row_ptr[node], end = row_ptr[node + 1];
    for (int base = beg; base < end; base += 64) {
        int k = base + lane;
        int mi = (k < end) ? csr[k] : zrow;
        int cnt = min(64, end - base);
        for (int j = 0; j < cnt; j += 16) {
            int idx[8]; short8 vv[8];
            #pragma unroll
            for (int u = 0; u < 8; u++) idx[u] = __shfl(mi, j + 2 * u + half);
            #pragma unroll
            for (int u = 0; u < 8; u++) vv[u] = *(const short8*)(h + (size_t)idx[u] * 256 + cl * 8);
            #pragma unroll
            for (int u = 0; u < 8; u++)
                #pragma unroll
                for (int c = 0; c < 8; c++) acc[c] += bf2f((unsigned short)vv[u][c]);
        }
    }
    #pragma unroll
    for (int c = 0; c < 8; c++) acc[c] += __shfl_xor(acc[c], 32);
    if (half == 0) {
        short8 o;
        #pragma unroll
        for (int c = 0; c < 8; c++) o[c] = (short)f2bf(acc[c]);
        *(short8*)(out + (size_t)node * 256 + cl * 8) = o;
    }
}

// HC=128: quarter-wave x ushort8 covers a row, 4 edges/instr.
__launch_bounds__(256)
__global__ void aggregate128(const unsigned short* __restrict__ h,
                             const int* __restrict__ row_ptr,
                             const int* __restrict__ csr,
                             unsigned short* __restrict__ out, int n, int zrow) {
    int node = blockIdx.x * 4 + (threadIdx.x >> 6);
    int lane = threadIdx.x & 63;
    if (node >= n) return;
    int qtr = lane >> 4;           // edge of the quad
    int cl = lane & 15;            // 8-col chunk
    float acc[8] = {0, 0, 0, 0, 0, 0, 0, 0};
    if (qtr == 0) {
        short8 sv = *(const short8*)(h + (size_t)node * 128 + cl * 8);
        #pragma unroll
        for (int c = 0; c < 8; c++) acc[c] = bf2f((unsigned short)sv[c]);
    }
    int beg = row_ptr[node], end = row_ptr[node + 1];
    for (int base = beg; base < end; base += 64) {
        int k = base + lane;
        int mi = (k < end) ? csr[k] : zrow;
        int cnt = min(64, end - base);
        for (int j = 0; j < cnt; j += 32) {
            int idx[8]; short8 vv[8];
            #pragma unroll
            for (int u = 0; u < 8; u++) idx[u] = __shfl(mi, j + 4 * u + qtr);
            #pragma unroll
            for (int u = 0; u < 8; u++) vv[u] = *(const short8*)(h + (size_t)idx[u] * 128 + cl * 8);
            #pragma unroll
            for (int u = 0; u < 8; u++)
                #pragma unroll
                for (int c = 0; c < 8; c++) acc[c] += bf2f((unsigned short)vv[u][c]);
        }
    }
    #pragma unroll
    for (int c = 0; c < 8; c++) {
        acc[c] += __shfl_xor(acc[c], 16);
        acc[c] += __shfl_xor(acc[c], 32);
    }
    if (qtr == 0) {
        short8 o;
        #pragma unroll
        for (int c = 0; c < 8; c++) o[c] = (short)f2bf(acc[c]);
        *(short8*)(out + (size_t)node * 128 + cl * 8) = o;
    }
}

// ---------------------------- wgemm ----------------------------------------
// C = epi(A[M,K] @ Bt[N,K]^T).  4 waves x 32 rows = 128 rows/block; A frags
// in registers (read once); per 64-col tile B staged to LDS.
// SCALE: 0 plain; 1: v=relu(di*acc+b)[+res/di], store di*v (ĥ out);
//        2: v=relu(di*acc+b)+res/di, store v (h out).

template<int K, int RELU, int RES, int OUTF32, int SCALE>
__launch_bounds__(256)
__global__ void wgemm(const unsigned short* __restrict__ A,
                      const unsigned short* __restrict__ Bt,
                      const float* __restrict__ bias,
                      const unsigned short* __restrict__ residual,
                      const float* __restrict__ dinv,
                      void* __restrict__ Cout,
                      int M, int N, int ntiles) {
    constexpr int KK = K / 32;
    constexpr int S = K + 8;
    constexpr int CPR = K / 8;
    __shared__ unsigned short Bs[64 * S];

    int tid = threadIdx.x;
    int wave = tid >> 6, lane = tid & 63;
    int r = lane & 15, q = lane >> 4;
    int mr = blockIdx.y * 128 + wave * 32;
    int nbase = blockIdx.x * ntiles * 64;

    short8 a[2][KK];
    #pragma unroll
    for (int mi = 0; mi < 2; mi++) {
        int arow = mr + mi * 16 + r;
        bool ok = arow < M;
        const unsigned short* ap = A + (size_t)(ok ? arow : 0) * K;
        #pragma unroll
        for (int kk = 0; kk < KK; kk++) {
            short8 v = *(const short8*)(ap + kk * 32 + q * 8);
            if (!ok) v = (short8){0, 0, 0, 0, 0, 0, 0, 0};
            a[mi][kk] = v;
        }
    }

    for (int t = 0; t < ntiles; t++) {
        int n0 = nbase + t * 64;
        if (t > 0) __syncthreads();
        #pragma unroll
        for (int pass = 0; pass < 64 * CPR / 256; pass++) {
            int f = pass * 256 + tid;
            int row = f / CPR, ch = f % CPR;
            *(short8*)&Bs[row * S + ch * 8] =
                *(const short8*)(Bt + (size_t)(n0 + row) * K + ch * 8);
        }
        __syncthreads();

        f32x4 acc[2][4];
        #pragma unroll
        for (int mi = 0; mi < 2; mi++)
            #pragma unroll
            for (int j = 0; j < 4; j++) acc[mi][j] = (f32x4){0.f, 0.f, 0.f, 0.f};

        #pragma unroll
        for (int kk = 0; kk < KK; kk++) {
            short8 b[4];
            #pragma unroll
            for (int j = 0; j < 4; j++)
                b[j] = *(short8*)&Bs[(j * 16 + r) * S + kk * 32 + q * 8];
            #pragma unroll
            for (int mi = 0; mi < 2; mi++)
                #pragma unroll
                for (int j = 0; j < 4; j++)
                    acc[mi][j] = __builtin_amdgcn_mfma_f32_16x16x32_bf16(a[mi][kk], b[j], acc[mi][j], 0, 0, 0);
        }

        float bb[4];
        #pragma unroll
        for (int j = 0; j < 4; j++) bb[j] = bias[n0 + j * 16 + r];

        #pragma unroll
        for (int mi = 0; mi < 2; mi++) {
            #pragma unroll
            for (int p = 0; p < 4; p++) {
                int row = mr + mi * 16 + q * 4 + p;
                if (row < M) {
                    float di = 1.f, rdi = 1.f;
                    if (SCALE) { di = dinv[row]; if (RES) rdi = 1.f / di; }
                    #pragma unroll
                    for (int j = 0; j < 4; j++) {
                        int col = n0 + j * 16 + r;
                        float v = (SCALE ? di * acc[mi][j][p] : acc[mi][j][p]) + bb[j];
                        if (RELU) v = fmaxf(v, 0.f);
                        if (RES) v += bf2f(residual[(size_t)row * N + col]) * rdi;
                        if (SCALE == 1) v *= di;
                        if (OUTF32) ((float*)Cout)[(size_t)row * N + col] = v;
                        else ((unsigned short*)Cout)[(size_t)row * N + col] = f2bf(v);
                    }
                }
            }
        }
    }
}

// ---------------------------- pool / LN ------------------------------------

// One wave per graph; lane covers 4 cols (ushort4 = 8B).
__launch_bounds__(256)
__global__ void pool_kernel(const unsigned short* __restrict__ h, const int* __restrict__ batch,
                            unsigned short* __restrict__ g0, int n, int G) {
    int g = blockIdx.x * 4 + (threadIdx.x >> 6);
    int lane = threadIdx.x & 63;
    if (g >= G) return;
    int lo = 0, hi = 0;
    if (lane == 0) {
        int a = 0, b = n;
        while (a < b) { int m = (a + b) >> 1; if (batch[m] < g) a = m + 1; else b = m; }
        lo = a;
        int a2 = a, b2 = n;
        while (a2 < b2) { int m = (a2 + b2) >> 1; if (batch[m] < g + 1) a2 = m + 1; else b2 = m; }
        hi = a2;
    }
    lo = __shfl(lo, 0); hi = __shfl(hi, 0);
    float a0 = 0.f, a1 = 0.f, a2 = 0.f, a3 = 0.f;
    for (int i = lo; i < hi; i++) {
        ushort4 v = *(const ushort4*)(h + (size_t)i * 256 + lane * 4);
        a0 += bf2f(v.x); a1 += bf2f(v.y); a2 += bf2f(v.z); a3 += bf2f(v.w);
    }
    float inv = 1.0f / fmaxf((float)(hi - lo), 1.0f);
    ushort4 o;
    o.x = f2bf(a0 * inv); o.y = f2bf(a1 * inv); o.z = f2bf(a2 * inv); o.w = f2bf(a3 * inv);
    *(ushort4*)(g0 + (size_t)g * 256 + lane * 4) = o;
}

__launch_bounds__(256)
__global__ void ln_kernel(const float* __restrict__ g2, const float* __restrict__ gamma,
                          const float* __restrict__ beta, float* __restrict__ out, int rows) {
    int row = blockIdx.x * 4 + (threadIdx.x >> 6);
    int lane = threadIdx.x & 63;
    if (row >= rows) return;
    const float* r = g2 + (size_t)row * 768;
    float v[12];
    float s = 0.f, s2 = 0.f;
    #pragma unroll
    for (int j = 0; j < 12; j++) {
        v[j] = r[lane + 64 * j];
        s += v[j];
        s2 += v[j] * v[j];
    }
    #pragma unroll
    for (int off = 32; off > 0; off >>= 1) {
        s += __shfl_down(s, off);
        s2 += __shfl_down(s2, off);
    }
    s = __shfl(s, 0);
    s2 = __shfl(s2, 0);
    float mu = s * (1.0f / 768.0f);
    float var = s2 * (1.0f / 768.0f) - mu * mu;
    float inv = rsqrtf(var + 1e-5f);
    #pragma unroll
    for (int j = 0; j < 12; j++) {
        int c = lane + 64 * j;
        out[(size_t)row * 768 + c] = (v[j] - mu) * inv * gamma[c] + beta[c];
    }
}

// ---------------------------------------------------------------------------

extern "C" void kernel_launch(void* const* d_in, const int* in_sizes, int n_in,
                              void* d_out, int out_size, void* d_ws, size_t ws_size,
                              hipStream_t stream) {
    const float* x    = (const float*)d_in[0];
    const int* eidx   = (const int*)d_in[1];
    const int* batch  = (const int*)d_in[2];
    const float* W1   = (const float*)d_in[3];
    const float* b1   = (const float*)d_in[4];
    const float* W2   = (const float*)d_in[5];
    const float* b2   = (const float*)d_in[6];
    const float* W3   = (const float*)d_in[7];
    const float* b3   = (const float*)d_in[8];
    const float* P1   = (const float*)d_in[9];
    const float* pb1  = (const float*)d_in[10];
    const float* P2   = (const float*)d_in[11];
    const float* pb2  = (const float*)d_in[12];
    const float* ln_g = (const float*)d_in[13];
    const float* ln_b = (const float*)d_in[14];
    float* out = (float*)d_out;

    const int N = in_sizes[2];            // 50000
    const int E = in_sizes[1] / 2;        // 800000
    const int F_IN = in_sizes[0] / N;     // 128
    const int H = in_sizes[4];            // 256
    const int D = in_sizes[12];           // 768
    const int G = out_size / D;           // 1024
    const int NPAD = (N + 127) & ~127;
    const int NB = (N + 511) / 512;       // scan blocks (<=128)

    const int* src = eidx;
    const int* dst = eidx + E;

    char* ws = (char*)d_ws;
    size_t off = 0;
    auto alloc = [&](size_t bytes) -> char* {
        char* p = ws + off;
        off = (off + bytes + 255) & ~(size_t)255;
        return p;
    };
    int*   cnt      = (int*)alloc((size_t)NPAD * 4);   // cnt & fill contiguous -> one memset
    int*   fill     = (int*)alloc((size_t)NPAD * 4);
    float* dinv     = (float*)alloc((size_t)NPAD * 4);
    int*   row_ptr  = (int*)alloc((size_t)(N + 1) * 4);
    int*   bsum     = (int*)alloc(128 * 4);
    int*   csr      = (int*)alloc((size_t)E * 4);
    unsigned short* xh  = (unsigned short*)alloc((size_t)(N + 1) * F_IN * 2);  // x̂, +dummy row
    unsigned short* Wt1 = (unsigned short*)alloc((size_t)F_IN * H * 2);
    unsigned short* Wt2 = (unsigned short*)alloc((size_t)H * H * 2);
    unsigned short* Wt3 = (unsigned short*)alloc((size_t)H * H * 2);
    unsigned short* Pt1 = (unsigned short*)alloc((size_t)H * H * 2);
    unsigned short* Pt2 = (unsigned short*)alloc((size_t)H * D * 2);
    unsigned short* t1  = (unsigned short*)alloc((size_t)N * F_IN * 2);        // Σ x̂
    unsigned short* tA  = (unsigned short*)alloc((size_t)N * H * 2);           // Σ ĥ (shared)
    unsigned short* hh1 = (unsigned short*)alloc((size_t)(N + 1) * H * 2);     // ĥ1, +dummy
    unsigned short* hh2 = (unsigned short*)alloc((size_t)(N + 1) * H * 2);     // ĥ2, +dummy
    unsigned short* h3  = (unsigned short*)alloc((size_t)N * H * 2);
    unsigned short* g0b = (unsigned short*)alloc((size_t)G * H * 2);
    unsigned short* g1b = (unsigned short*)alloc((size_t)G * H * 2);
    float* g2 = (float*)alloc((size_t)G * D * 4);
    (void)ws_size; (void)n_in;

    // --- CSR build -----------------------------------------------------------
    hipMemsetAsync(cnt, 0, (size_t)2 * NPAD * 4, stream);
    count_kernel<<<(E + 255) / 256, 256, 0, stream>>>(dst, E, cnt);
    scanA<<<NB, 512, 0, stream>>>(cnt, N, bsum, dinv);
    scanB<<<1, 256, 0, stream>>>(bsum, NB, N, row_ptr,
                                 xh + (size_t)N * F_IN, hh1 + (size_t)N * H, hh2 + (size_t)N * H);
    scanC<<<NB, 512, 0, stream>>>(cnt, N, bsum, row_ptr);
    scatter_kernel<<<(E + 255) / 256, 256, 0, stream>>>(src, dst, E, row_ptr, fill, csr);

    // --- conversions ---------------------------------------------------------
    convert_x<<<(N * F_IN / 4 + 255) / 256, 256, 0, stream>>>(x, dinv, xh, N * F_IN / 4, 5);
    {
        int tot = F_IN * H + 3 * H * H + H * D;
        convert_weights<<<(tot + 255) / 256, 256, 0, stream>>>(W1, W2, W3, P1, P2,
                                                               Wt1, Wt2, Wt3, Pt1, Pt2,
                                                               F_IN, H, D);
    }

    // --- GCN layers (aggregate-first, ĥ-space) ------------------------------
    int agg_grid = (N + 3) / 4;
    int mtiles = (N + 127) / 128;

    // layer 1: t1 = x̂[i] + Σ x̂[src]; ĥ1 = di*relu(di*(t1 W1) + b1)
    aggregate128<<<agg_grid, 256, 0, stream>>>(xh, row_ptr, csr, t1, N, N);
    wgemm<128, 1, 0, 0, 1><<<dim3(2, mtiles), 256, 0, stream>>>(t1, Wt1, b1, nullptr, dinv, hh1, N, H, 2);

    // layer 2: t2 = ĥ1[i] + Σ ĥ1[src]; ĥ2 = di*(relu(di*(t2 W2)+b2) + ĥ1/di)
    aggregate256<<<agg_grid, 256, 0, stream>>>(hh1, row_ptr, csr, tA, N, N);
    wgemm<256, 1, 1, 0, 1><<<dim3(2, mtiles), 256, 0, stream>>>(tA, Wt2, b2, hh1, dinv, hh2, N, H, 2);

    // layer 3: t3 = ĥ2[i] + Σ ĥ2[src]; h3 = relu(di*(t3 W3)+b3) + ĥ2/di
    aggregate256<<<agg_grid, 256, 0, stream>>>(hh2, row_ptr, csr, tA, N, N);
    wgemm<256, 1, 1, 0, 2><<<dim3(2, mtiles), 256, 0, stream>>>(tA, Wt3, b3, hh2, dinv, h3, N, H, 2);

    // --- pool + MLP + LN -----------------------------------------------------
    pool_kernel<<<(G + 3) / 4, 256, 0, stream>>>(h3, batch, g0b, N, G);
    wgemm<256, 1, 0, 0, 0><<<dim3(4, G / 128), 256, 0, stream>>>(g0b, Pt1, pb1, nullptr, nullptr, g1b, G, H, 1);
    wgemm<256, 0, 0, 1, 0><<<dim3(12, G / 128), 256, 0, stream>>>(g1b, Pt2, pb2, nullptr, nullptr, g2, G, D, 1);
    ln_kernel<<<G / 4, 256, 0, stream>>>(g2, ln_g, ln_b, out, G);
}